// Round 3
// baseline (229.921 us; speedup 1.0000x reference)
//
#include <hip/hip_runtime.h>
#include <hip/hip_bf16.h>
#include <cstdint>

// ---------- types ----------
typedef __bf16 bf8 __attribute__((ext_vector_type(8)));
typedef __bf16 bf4 __attribute__((ext_vector_type(4)));
typedef float  f4  __attribute__((ext_vector_type(4)));

typedef const void __attribute__((address_space(1)))* as1_cvp;
typedef void       __attribute__((address_space(3)))* as3_vp;

#define NEG_INF_F 1000000000000.0f

__device__ __forceinline__ void lds_load16(const __bf16* g, __bf16* l) {
    // async global->LDS, 16B per lane; LDS dst = wave-uniform base + lane*16
    __builtin_amdgcn_global_load_lds((as1_cvp)g, (as3_vp)l, 16, 0, 0);
}

// ---------- MFMA GEMM core (proj), 2-phase double-buffered, swapped operands --
// C(128x128) += A(128xK) * Bt(128xK)^T, bf16, BK=32, 4 waves (2x2 of 64x64).
// mfma(bfr, af): C row m = lane&15 (A-row), C col n = quad*4 + reg (Bt-row).
// Pipeline (T3-minimum): stage(k+1) issued BEFORE compute(k); one barrier/iter.
__device__ __forceinline__ void gemm_tile_core_swapped(
    const __bf16* __restrict__ Atile, const __bf16* __restrict__ Btile,
    int lda, int ldb, int Ktot,
    __bf16* sA, __bf16* sB, f4 acc[4][4])   // sA/sB each 2*128*32 elems
{
    const int t    = threadIdx.x;
    const int wave = t >> 6;
    const int lane = t & 63;
    const int quad = lane >> 4;
    const int m16  = lane & 15;
    const int wm   = (wave >> 1) * 64;
    const int wn   = (wave & 1) * 64;

    // per-thread staging coords (two 16B chunks per matrix per thread)
    const int f0   = t;            // chunk ids t and 256+t
    const int row0 = f0 >> 2;
    const int ch0  = (f0 & 3) * 8;
    const int f1   = 256 + t;
    const int row1 = f1 >> 2;
    const int ch1  = (f1 & 3) * 8;
    const int l0   = (wave * 64) * 8;          // LDS elem offset, chunk set 0
    const int l1   = (256 + wave * 64) * 8;    // LDS elem offset, chunk set 1

    // ---- prologue: stage k-tile 0 into buffer 0 ----
    lds_load16(Atile + (size_t)row0 * lda + ch0, sA + l0);
    lds_load16(Btile + (size_t)row0 * ldb + ch0, sB + l0);
    lds_load16(Atile + (size_t)row1 * lda + ch1, sA + l1);
    lds_load16(Btile + (size_t)row1 * ldb + ch1, sB + l1);
    __syncthreads();   // vmcnt(0): tile 0 resident

    const int nIter = Ktot >> 5;
    for (int k = 0; k < nIter; ++k) {
        const int cur = (k & 1) * 4096;        // 128*32 elems per buffer
        // ---- issue async stage of tile k+1 into the other buffer ----
        if (k + 1 < nIter) {
            const int nxt = ((k + 1) & 1) * 4096;
            const int k0n = (k + 1) << 5;
            lds_load16(Atile + (size_t)row0 * lda + k0n + ch0, sA + nxt + l0);
            lds_load16(Btile + (size_t)row0 * ldb + k0n + ch0, sB + nxt + l0);
            lds_load16(Atile + (size_t)row1 * lda + k0n + ch1, sA + nxt + l1);
            lds_load16(Btile + (size_t)row1 * ldb + k0n + ch1, sB + nxt + l1);
        }

        // ---- compute tile k from buffer cur ----
        bf8 af[4], bfr[4];
#pragma unroll
        for (int mi = 0; mi < 4; ++mi)
            af[mi] = *(const bf8*)(sA + cur + (wm + mi * 16 + m16) * 32 + quad * 8);
#pragma unroll
        for (int ni = 0; ni < 4; ++ni)
            bfr[ni] = *(const bf8*)(sB + cur + (wn + ni * 16 + m16) * 32 + quad * 8);
#pragma unroll
        for (int mi = 0; mi < 4; ++mi)
#pragma unroll
            for (int ni = 0; ni < 4; ++ni)
                acc[mi][ni] = __builtin_amdgcn_mfma_f32_16x16x32_bf16(
                    bfr[ni], af[mi], acc[mi][ni], 0, 0, 0);

        // one barrier per iter: drains stage(k+1) (vmcnt) and guarantees all
        // waves finished reading buffer cur before iter k+1 restages into it
        __syncthreads();
    }
}

// ---------- kernel 1: fused cast (A fp32->bf16) + W transpose ----------
__global__ __launch_bounds__(256) void prep_kernel(
    const float* __restrict__ lhs, __bf16* __restrict__ Abf,
    const float* __restrict__ W,   __bf16* __restrict__ Wt)
{
    __shared__ __bf16 tile[32][33];
    const int t  = threadIdx.x;
    int bx = blockIdx.x;
    if (bx < 6144) {
        // cast: 6144 * 256 * 4 floats = exactly 16*512*768
        const int idx = bx * 256 + t;
        const float4 v = reinterpret_cast<const float4*>(lhs)[idx];
        bf4 o = { (__bf16)v.x, (__bf16)v.y, (__bf16)v.z, (__bf16)v.w };
        reinterpret_cast<bf4*>(Abf)[idx] = o;
    } else {
        // transpose W (768x1152) -> Wt bf16 (1152x768)
        bx -= 6144;                       // 0..863 = 36*24
        const int n0 = (bx % 36) * 32;
        const int k0 = (bx / 36) * 32;
        const int tx = t & 31;
        const int ty = t >> 5;            // 0..7
#pragma unroll
        for (int r = 0; r < 32; r += 8)
            tile[ty + r][tx] = (__bf16)W[(size_t)(k0 + ty + r) * 1152 + n0 + tx];
        __syncthreads();
#pragma unroll
        for (int r = 0; r < 32; r += 8)
            Wt[(size_t)(n0 + ty + r) * 768 + k0 + tx] = tile[tx][ty + r];
    }
}

// ---------- kernel 2: proj GEMM + bias + RoPE -> q/k bf16 (b,e,s,64) ----------
// Swapped-operand layout: output col n = colTile+wn+ni*16+quad*4+r lands on the
// accumulator reg index -> RoPE pair (d,d^1) is IN-THREAD (no shfl), bias is a
// float4 load, and q/k store is one 8B bf16x4 per (mi,ni).
__global__ __launch_bounds__(256) void proj_rope_kernel(
    const __bf16* __restrict__ A,    // 8192 x 768
    const __bf16* __restrict__ Wt,   // 1152 x 768
    const float*  __restrict__ bias, // 1152
    __bf16* __restrict__ qbuf, __bf16* __restrict__ kbuf)
{
    __shared__ __bf16 sA[2 * 128 * 32];
    __shared__ __bf16 sB[2 * 128 * 32];
    f4 acc[4][4] = {};

    const int rowTile = blockIdx.y * 128;   // over M=8192
    const int colTile = blockIdx.x * 128;   // over N=1152
    gemm_tile_core_swapped(A + (size_t)rowTile * 768, Wt + (size_t)colTile * 768,
                           768, 768, 768, sA, sB, acc);

    const int t = threadIdx.x, wave = t >> 6, lane = t & 63;
    const int quad = lane >> 4, m16 = lane & 15;
    const int wm = (wave >> 1) * 64, wn = (wave & 1) * 64;

#pragma unroll
    for (int ni = 0; ni < 4; ++ni) {
        const int gc0 = colTile + wn + ni * 16 + quad * 4;  // 4-aligned col base
        const int e   = gc0 >> 7;          // ent 0..8
        const int d0  = gc0 & 63;          // dim base within q/k (mult of 4)
        const int qk  = (gc0 >> 6) & 1;    // 0=q, 1=k
        const float4 bv = *reinterpret_cast<const float4*>(bias + gc0);
        // theta_i = 10000^{-i/32} = 2^{-i*log2(10000)/32}
        const float th0 = exp2f((float)(d0 >> 1)       * -0.4152410118609203f);
        const float th1 = exp2f((float)((d0 >> 1) + 1) * -0.4152410118609203f);
        __bf16* base = (qk ? kbuf : qbuf);
#pragma unroll
        for (int mi = 0; mi < 4; ++mi) {
            const int gm = rowTile + wm + mi * 16 + m16;
            const int bb = gm >> 9;      // batch
            const int s  = gm & 511;     // position
            const float sf = (float)s;
            float v0 = acc[mi][ni][0] + bv.x;
            float v1 = acc[mi][ni][1] + bv.y;
            float v2 = acc[mi][ni][2] + bv.z;
            float v3 = acc[mi][ni][3] + bv.w;
            float sn0, cs0, sn1, cs1;
            __sincosf(sf * th0, &sn0, &cs0);
            __sincosf(sf * th1, &sn1, &cs1);
            bf4 o = { (__bf16)(v0 * cs0 - v1 * sn0),
                      (__bf16)(v1 * cs0 + v0 * sn0),
                      (__bf16)(v2 * cs1 - v3 * sn1),
                      (__bf16)(v3 * cs1 + v2 * sn1) };
            *reinterpret_cast<bf4*>(
                base + ((size_t)((bb * 9 + e) * 512 + s)) * 64 + d0) = o;
        }
    }
}

// ---------- kernel 3: barrier-free streaming logits with causal-tile skip ----
// grid (4, 144). No LDS, no __syncthreads. Q frags in registers; K frags
// loaded straight from global (64 KB/be -> L2-hit). Swapped-operand MFMA.
// Tiles fully below the diagonal (all n < m) skip K-loads+MFMA: the -1e12
// subtraction absorbs acc exactly in f32 (ulp at 1e12 = 65536 >> |acc|),
// so the stored bits match the reference bit-for-bit.
__global__ __launch_bounds__(256, 3) void logits_kernel(
    const __bf16* __restrict__ qbuf, const __bf16* __restrict__ kbuf,
    const float* __restrict__ amask, float* __restrict__ out)
{
    const int t    = threadIdx.x;
    const int wave = t >> 6;
    const int lane = t & 63;
    const int quad = lane >> 4;
    const int m16  = lane & 15;
    const int wm   = (wave >> 1) * 64;   // row offset within the 128-row tile
    const int ncol = (wave & 1) * 256;   // column half owned by this wave

    const int be = blockIdx.y;           // 0..143
    const int b  = be / 9;
    const int rowTile = blockIdx.x * 128;
    const int rowbase = rowTile + wm;

    // number of fully-masked 64-col chunks (prefix in c): chunk masked iff
    // ncol + 64c + 63 < rowbase  <=>  c < (rowbase - ncol)/64  (both 64-aligned)
    int c0 = (rowbase - ncol) >> 6;
    c0 = c0 < 0 ? 0 : (c0 > 4 ? 4 : c0);

    const __bf16* Qg = qbuf + (size_t)be * 512 * 64 + (size_t)rowbase * 64;
    const __bf16* Kg = kbuf + (size_t)be * 512 * 64;

    // ---- Q fragments: resident in registers for the whole kernel ----
    bf8 af[2][4];
#pragma unroll
    for (int kp = 0; kp < 2; ++kp)
#pragma unroll
        for (int mi = 0; mi < 4; ++mi)
            af[kp][mi] = *reinterpret_cast<const bf8*>(
                Qg + (mi * 16 + m16) * 64 + kp * 32 + quad * 8);

    const float* amr  = amask + b * 512;
    float*       outw = out + ((size_t)(be * 512 + rowbase) << 9);

#pragma unroll
    for (int c = 0; c < 4; ++c) {
        const int n0 = ncol + c * 64;
        if (c >= c0) {
            // ---- live tile: K frags from global, MFMA, full epilogue ----
            const __bf16* Kc = Kg + (size_t)n0 * 64;
            bf8 bfr[2][4];
#pragma unroll
            for (int kp = 0; kp < 2; ++kp)
#pragma unroll
                for (int ni = 0; ni < 4; ++ni)
                    bfr[kp][ni] = *reinterpret_cast<const bf8*>(
                        Kc + (ni * 16 + m16) * 64 + kp * 32 + quad * 8);

            f4 acc[4][4] = {};
#pragma unroll
            for (int kp = 0; kp < 2; ++kp)
#pragma unroll
                for (int mi = 0; mi < 4; ++mi)
#pragma unroll
                    for (int ni = 0; ni < 4; ++ni)
                        acc[mi][ni] = __builtin_amdgcn_mfma_f32_16x16x32_bf16(
                            bfr[kp][ni], af[kp][mi], acc[mi][ni], 0, 0, 0);

#pragma unroll
            for (int ni = 0; ni < 4; ++ni) {
                const int nq = n0 + ni * 16 + quad * 4;
                const float4 pv = *reinterpret_cast<const float4*>(amr + nq);
                const float pp[4] = { pv.x, pv.y, pv.z, pv.w };
#pragma unroll
                for (int mi = 0; mi < 4; ++mi) {
                    const int m = rowbase + mi * 16 + m16;
                    const f4 a = acc[mi][ni];
                    float4 res;
                    float* rp = &res.x;
#pragma unroll
                    for (int r = 0; r < 4; ++r) {
                        float v = a[r] * pp[r] - (1.0f - pp[r]) * NEG_INF_F;
                        if (nq + r < m) v -= NEG_INF_F;   // tril(-1) mask
                        rp[r] = v * 0.125f;
                    }
                    *reinterpret_cast<float4*>(
                        outw + (((size_t)(mi * 16 + m16)) << 9) + nq) = res;
                }
            }
        } else {
            // ---- fully-masked tile: constant epilogue (acc == 0) ----
#pragma unroll
            for (int ni = 0; ni < 4; ++ni) {
                const int nq = n0 + ni * 16 + quad * 4;
                const float4 pv = *reinterpret_cast<const float4*>(amr + nq);
                const float pp[4] = { pv.x, pv.y, pv.z, pv.w };
                float4 res;
                float* rp = &res.x;
#pragma unroll
                for (int r = 0; r < 4; ++r)
                    rp[r] = (-(1.0f - pp[r]) * NEG_INF_F - NEG_INF_F) * 0.125f;
#pragma unroll
                for (int mi = 0; mi < 4; ++mi)
                    *reinterpret_cast<float4*>(
                        outw + (((size_t)(mi * 16 + m16)) << 9) + nq) = res;
            }
        }
    }
}

// ---------- launch ----------
extern "C" void kernel_launch(void* const* d_in, const int* in_sizes, int n_in,
                              void* d_out, int out_size, void* d_ws, size_t ws_size,
                              hipStream_t stream) {
    const float* lhs   = (const float*)d_in[0];  // 16*512*768
    const float* amask = (const float*)d_in[1];  // 16*512
    const float* W     = (const float*)d_in[2];  // 768*1152
    const float* bias  = (const float*)d_in[3];  // 1152
    float* out = (float*)d_out;

    char* ws = (char*)d_ws;
    __bf16* Abf = (__bf16*)ws;                       // 8192*768*2   = 12,582,912 B
    __bf16* Wt  = (__bf16*)(ws + 12582912);          // 1152*768*2   =  1,769,472 B
    __bf16* qb  = (__bf16*)(ws + 14352384);          // 144*512*64*2 =  9,437,184 B
    __bf16* kb  = (__bf16*)(ws + 23789568);          // 144*512*64*2 =  9,437,184 B

    prep_kernel<<<7008, 256, 0, stream>>>(lhs, Abf, W, Wt);   // 6144 cast + 864 transpose
    proj_rope_kernel<<<dim3(9, 64), 256, 0, stream>>>(Abf, Wt, bias, qb, kb);
    logits_kernel<<<dim3(4, 144), 256, 0, stream>>>(qb, kb, amask, out);
}

// Round 4
// 229.632 us; speedup vs baseline: 1.0013x; 1.0013x over previous
//
#include <hip/hip_runtime.h>
#include <hip/hip_bf16.h>
#include <cstdint>

// ---------- types ----------
typedef __bf16 bf8 __attribute__((ext_vector_type(8)));
typedef __bf16 bf4 __attribute__((ext_vector_type(4)));
typedef float  f4  __attribute__((ext_vector_type(4)));

typedef const void __attribute__((address_space(1)))* as1_cvp;
typedef void       __attribute__((address_space(3)))* as3_vp;

#define NEG_INF_F 1000000000000.0f

__device__ __forceinline__ void lds_load16(const __bf16* g, __bf16* l) {
    // async global->LDS, 16B per lane; LDS dst = wave-uniform base + lane*16
    __builtin_amdgcn_global_load_lds((as1_cvp)g, (as3_vp)l, 16, 0, 0);
}

// ---------- kernel 1: W (768x1152) fp32 -> Wt bf16 (1152x768) ----------
__global__ __launch_bounds__(256) void transpose_w_kernel(
    const float* __restrict__ W, __bf16* __restrict__ Wt)
{
    __shared__ __bf16 tile[32][33];
    const int n0 = blockIdx.x * 32;
    const int k0 = blockIdx.y * 32;
    const int tx = threadIdx.x & 31;
    const int ty = threadIdx.x >> 5;   // 0..7
#pragma unroll
    for (int r = 0; r < 32; r += 8)
        tile[ty + r][tx] = (__bf16)W[(size_t)(k0 + ty + r) * 1152 + n0 + tx];
    __syncthreads();
#pragma unroll
    for (int r = 0; r < 32; r += 8)
        Wt[(size_t)(n0 + ty + r) * 768 + k0 + tx] = tile[tx][ty + r];
}

// ---------- kernel 2: proj GEMM (A fp32 in, cast fused) + bias + RoPE ------
// grid 576 1-D; XCD-bijective swizzle (576 = 8*72) groups the 9 col-tiles of
// each A row-panel on one XCD -> A re-reads are L2 hits.
// A is reg-staged (fp32 global -> cvt bf16 -> ds_write) since global_load_lds
// can't convert; B (Wt, bf16) stays async global_load_lds. 2-phase dbuf:
// stage(k+1) issued before compute(k), A ds_write after compute, 1 barrier/it.
// Swapped-operand MFMA: C row m = lane&15, C col n = quad*4 + reg ->
// RoPE pair (d, d^1) is IN-THREAD; q/k store is one 8B bf16x4.
__global__ __launch_bounds__(256) void proj_rope_kernel(
    const float*  __restrict__ A,    // 8192 x 768 fp32
    const __bf16* __restrict__ Wt,   // 1152 x 768 bf16
    const float*  __restrict__ bias, // 1152
    __bf16* __restrict__ qbuf, __bf16* __restrict__ kbuf)
{
    __shared__ __bf16 sA[2 * 128 * 32];
    __shared__ __bf16 sB[2 * 128 * 32];
    f4 acc[4][4] = {};

    const int bid = blockIdx.x;
    const int wid = (bid & 7) * 72 + (bid >> 3);   // XCD swizzle (bijective)
    const int rowTile = (wid / 9) * 128;           // over M=8192
    const int colTile = (wid % 9) * 128;           // over N=1152

    const float*  Ag = A  + (size_t)rowTile * 768;
    const __bf16* Bg = Wt + (size_t)colTile * 768;

    const int t    = threadIdx.x;
    const int wave = t >> 6;
    const int lane = t & 63;
    const int quad = lane >> 4;
    const int m16  = lane & 15;
    const int wm   = (wave >> 1) * 64;
    const int wn   = (wave & 1) * 64;

    // staging coords: chunk f (0..511) -> row=f>>2, k-offset=(f&3)*8
    const int f0 = t,       row0 = f0 >> 2, k80 = (f0 & 3) * 8;
    const int f1 = t + 256, row1 = f1 >> 2, k81 = (f1 & 3) * 8;
    const int lb0 = (wave * 64) * 8;         // B glds dst, chunk set 0
    const int lb1 = (256 + wave * 64) * 8;   // B glds dst, chunk set 1

    // ---- prologue: stage k-tile 0 into buffer 0 ----
    {
        const float4 a00 = *(const float4*)(Ag + (size_t)row0 * 768 + k80);
        const float4 a01 = *(const float4*)(Ag + (size_t)row0 * 768 + k80 + 4);
        const float4 a10 = *(const float4*)(Ag + (size_t)row1 * 768 + k81);
        const float4 a11 = *(const float4*)(Ag + (size_t)row1 * 768 + k81 + 4);
        lds_load16(Bg + (size_t)row0 * 768 + k80, sB + lb0);
        lds_load16(Bg + (size_t)row1 * 768 + k81, sB + lb1);
        bf8 w0 = { (__bf16)a00.x, (__bf16)a00.y, (__bf16)a00.z, (__bf16)a00.w,
                   (__bf16)a01.x, (__bf16)a01.y, (__bf16)a01.z, (__bf16)a01.w };
        bf8 w1 = { (__bf16)a10.x, (__bf16)a10.y, (__bf16)a10.z, (__bf16)a10.w,
                   (__bf16)a11.x, (__bf16)a11.y, (__bf16)a11.z, (__bf16)a11.w };
        *(bf8*)(sA + f0 * 8) = w0;
        *(bf8*)(sA + f1 * 8) = w1;
    }
    __syncthreads();   // tile 0 resident (vmcnt+lgkm drained by barrier)

    const int nIter = 24;   // K=768 / BK=32
    for (int k = 0; k < nIter; ++k) {
        const int cur = (k & 1) * 4096;
        const int nxt = ((k + 1) & 1) * 4096;

        // ---- issue stage of tile k+1: A global loads + B async glds ----
        float4 a00, a01, a10, a11;
        const bool pf = (k + 1 < nIter);
        if (pf) {
            const int kn = (k + 1) << 5;
            a00 = *(const float4*)(Ag + (size_t)row0 * 768 + kn + k80);
            a01 = *(const float4*)(Ag + (size_t)row0 * 768 + kn + k80 + 4);
            a10 = *(const float4*)(Ag + (size_t)row1 * 768 + kn + k81);
            a11 = *(const float4*)(Ag + (size_t)row1 * 768 + kn + k81 + 4);
            lds_load16(Bg + (size_t)row0 * 768 + kn + k80, sB + nxt + lb0);
            lds_load16(Bg + (size_t)row1 * 768 + kn + k81, sB + nxt + lb1);
        }

        // ---- compute tile k from buffer cur ----
        bf8 af[4], bfr[4];
#pragma unroll
        for (int mi = 0; mi < 4; ++mi)
            af[mi] = *(const bf8*)(sA + cur + (wm + mi * 16 + m16) * 32 + quad * 8);
#pragma unroll
        for (int ni = 0; ni < 4; ++ni)
            bfr[ni] = *(const bf8*)(sB + cur + (wn + ni * 16 + m16) * 32 + quad * 8);
#pragma unroll
        for (int mi = 0; mi < 4; ++mi)
#pragma unroll
            for (int ni = 0; ni < 4; ++ni)
                acc[mi][ni] = __builtin_amdgcn_mfma_f32_16x16x32_bf16(
                    bfr[ni], af[mi], acc[mi][ni], 0, 0, 0);

        // ---- late A write (loads had the compute phase to land) ----
        if (pf) {
            bf8 w0 = { (__bf16)a00.x, (__bf16)a00.y, (__bf16)a00.z, (__bf16)a00.w,
                       (__bf16)a01.x, (__bf16)a01.y, (__bf16)a01.z, (__bf16)a01.w };
            bf8 w1 = { (__bf16)a10.x, (__bf16)a10.y, (__bf16)a10.z, (__bf16)a10.w,
                       (__bf16)a11.x, (__bf16)a11.y, (__bf16)a11.z, (__bf16)a11.w };
            *(bf8*)(sA + nxt + f0 * 8) = w0;
            *(bf8*)(sA + nxt + f1 * 8) = w1;
        }
        __syncthreads();   // drains B glds + A ds_write; frees buffer cur
    }

    // ---- epilogue: bias + RoPE, in-thread pairs, bf16x4 stores ----
#pragma unroll
    for (int ni = 0; ni < 4; ++ni) {
        const int gc0 = colTile + wn + ni * 16 + quad * 4;  // 4-aligned col base
        const int e   = gc0 >> 7;          // ent 0..8
        const int d0  = gc0 & 63;          // dim base within q/k (mult of 4)
        const int qk  = (gc0 >> 6) & 1;    // 0=q, 1=k
        const float4 bv = *reinterpret_cast<const float4*>(bias + gc0);
        // theta_i = 10000^{-i/32} = 2^{-i*log2(10000)/32}
        const float th0 = exp2f((float)(d0 >> 1)       * -0.4152410118609203f);
        const float th1 = exp2f((float)((d0 >> 1) + 1) * -0.4152410118609203f);
        __bf16* base = (qk ? kbuf : qbuf);
#pragma unroll
        for (int mi = 0; mi < 4; ++mi) {
            const int gm = rowTile + wm + mi * 16 + m16;
            const int bb = gm >> 9;      // batch
            const int s  = gm & 511;     // position
            const float sf = (float)s;
            float v0 = acc[mi][ni][0] + bv.x;
            float v1 = acc[mi][ni][1] + bv.y;
            float v2 = acc[mi][ni][2] + bv.z;
            float v3 = acc[mi][ni][3] + bv.w;
            float sn0, cs0, sn1, cs1;
            __sincosf(sf * th0, &sn0, &cs0);
            __sincosf(sf * th1, &sn1, &cs1);
            bf4 o = { (__bf16)(v0 * cs0 - v1 * sn0),
                      (__bf16)(v1 * cs0 + v0 * sn0),
                      (__bf16)(v2 * cs1 - v3 * sn1),
                      (__bf16)(v3 * cs1 + v2 * sn1) };
            *reinterpret_cast<bf4*>(
                base + ((size_t)((bb * 9 + e) * 512 + s)) * 64 + d0) = o;
        }
    }
}

// ---------- kernel 3: barrier-free streaming logits with causal-tile skip ----
// grid (4, 144). No LDS, no __syncthreads. Q frags in registers; K frags
// loaded straight from global (64 KB/be -> L2/L3-hit). Swapped-operand MFMA.
// Tiles fully below the diagonal skip K-loads+MFMA: the -1e12 subtraction
// absorbs acc exactly in f32 (ulp at 1e12 = 65536 >> |acc|) -> bits match.
__global__ __launch_bounds__(256, 3) void logits_kernel(
    const __bf16* __restrict__ qbuf, const __bf16* __restrict__ kbuf,
    const float* __restrict__ amask, float* __restrict__ out)
{
    const int t    = threadIdx.x;
    const int wave = t >> 6;
    const int lane = t & 63;
    const int quad = lane >> 4;
    const int m16  = lane & 15;
    const int wm   = (wave >> 1) * 64;   // row offset within the 128-row tile
    const int ncol = (wave & 1) * 256;   // column half owned by this wave

    const int be = blockIdx.y;           // 0..143
    const int b  = be / 9;
    const int rowTile = blockIdx.x * 128;
    const int rowbase = rowTile + wm;

    // fully-masked 64-col chunk prefix: chunk c masked iff ncol+64c+63 < rowbase
    int c0 = (rowbase - ncol) >> 6;
    c0 = c0 < 0 ? 0 : (c0 > 4 ? 4 : c0);

    const __bf16* Qg = qbuf + (size_t)be * 512 * 64 + (size_t)rowbase * 64;
    const __bf16* Kg = kbuf + (size_t)be * 512 * 64;

    // ---- Q fragments: resident in registers for the whole kernel ----
    bf8 af[2][4];
#pragma unroll
    for (int kp = 0; kp < 2; ++kp)
#pragma unroll
        for (int mi = 0; mi < 4; ++mi)
            af[kp][mi] = *reinterpret_cast<const bf8*>(
                Qg + (mi * 16 + m16) * 64 + kp * 32 + quad * 8);

    const float* amr  = amask + b * 512;
    float*       outw = out + ((size_t)(be * 512 + rowbase) << 9);

#pragma unroll
    for (int c = 0; c < 4; ++c) {
        const int n0 = ncol + c * 64;
        if (c >= c0) {
            // ---- live tile: K frags from global, MFMA, full epilogue ----
            const __bf16* Kc = Kg + (size_t)n0 * 64;
            bf8 bfr[2][4];
#pragma unroll
            for (int kp = 0; kp < 2; ++kp)
#pragma unroll
                for (int ni = 0; ni < 4; ++ni)
                    bfr[kp][ni] = *reinterpret_cast<const bf8*>(
                        Kc + (ni * 16 + m16) * 64 + kp * 32 + quad * 8);

            f4 acc[4][4] = {};
#pragma unroll
            for (int kp = 0; kp < 2; ++kp)
#pragma unroll
                for (int mi = 0; mi < 4; ++mi)
#pragma unroll
                    for (int ni = 0; ni < 4; ++ni)
                        acc[mi][ni] = __builtin_amdgcn_mfma_f32_16x16x32_bf16(
                            bfr[kp][ni], af[kp][mi], acc[mi][ni], 0, 0, 0);

#pragma unroll
            for (int ni = 0; ni < 4; ++ni) {
                const int nq = n0 + ni * 16 + quad * 4;
                const float4 pv = *reinterpret_cast<const float4*>(amr + nq);
                const float pp[4] = { pv.x, pv.y, pv.z, pv.w };
#pragma unroll
                for (int mi = 0; mi < 4; ++mi) {
                    const int m = rowbase + mi * 16 + m16;
                    const f4 a = acc[mi][ni];
                    float4 res;
                    float* rp = &res.x;
#pragma unroll
                    for (int r = 0; r < 4; ++r) {
                        float v = a[r] * pp[r] - (1.0f - pp[r]) * NEG_INF_F;
                        if (nq + r < m) v -= NEG_INF_F;   // tril(-1) mask
                        rp[r] = v * 0.125f;
                    }
                    *reinterpret_cast<float4*>(
                        outw + (((size_t)(mi * 16 + m16)) << 9) + nq) = res;
                }
            }
        } else {
            // ---- fully-masked tile: constant epilogue (acc == 0) ----
#pragma unroll
            for (int ni = 0; ni < 4; ++ni) {
                const int nq = n0 + ni * 16 + quad * 4;
                const float4 pv = *reinterpret_cast<const float4*>(amr + nq);
                const float pp[4] = { pv.x, pv.y, pv.z, pv.w };
                float4 res;
                float* rp = &res.x;
#pragma unroll
                for (int r = 0; r < 4; ++r)
                    rp[r] = (-(1.0f - pp[r]) * NEG_INF_F - NEG_INF_F) * 0.125f;
#pragma unroll
                for (int mi = 0; mi < 4; ++mi)
                    *reinterpret_cast<float4*>(
                        outw + (((size_t)(mi * 16 + m16)) << 9) + nq) = res;
            }
        }
    }
}

// ---------- launch ----------
extern "C" void kernel_launch(void* const* d_in, const int* in_sizes, int n_in,
                              void* d_out, int out_size, void* d_ws, size_t ws_size,
                              hipStream_t stream) {
    const float* lhs   = (const float*)d_in[0];  // 16*512*768
    const float* amask = (const float*)d_in[1];  // 16*512
    const float* W     = (const float*)d_in[2];  // 768*1152
    const float* bias  = (const float*)d_in[3];  // 1152
    float* out = (float*)d_out;

    char* ws = (char*)d_ws;
    __bf16* Wt = (__bf16*)ws;                        // 1152*768*2   = 1,769,472 B
    __bf16* qb = (__bf16*)(ws + 1769472);            // 144*512*64*2 = 9,437,184 B
    __bf16* kb = (__bf16*)(ws + 11206656);           // 144*512*64*2 = 9,437,184 B

    transpose_w_kernel<<<dim3(36, 24), 256, 0, stream>>>(W, Wt);
    proj_rope_kernel<<<576, 256, 0, stream>>>(lhs, Wt, bias, qb, kb);
    logits_kernel<<<dim3(4, 144), 256, 0, stream>>>(qb, kb, amask, out);
}